// Round 8
// baseline (2173.004 us; speedup 1.0000x reference)
//
#include <hip/hip_runtime.h>
#include <math.h>

#define NN 1048576
#define EE 4194304
#define TPB 256
#define NBLK 2048
#define NBUCK 256
#define BNODES 4096          // nodes per bucket (NN / NBUCK)
#define CAP 20480            // bucket edge capacity (mean 16384, sigma~128)
constexpr float BN_EPS = 1e-5f;

typedef _Float16 half8  __attribute__((ext_vector_type(8)));
typedef unsigned int u32;

// ---- workspace layout (bytes) ----
// Request-rate model (r0-r7): k_layerk time ~ random 16B requests / 63G/s.
// Lane-pair gather: 2 adjacent lanes load the two 16B halves of one 32B row in
// ONE instruction -> TA coalesces to one transaction/edge (8M -> 4M reqs/layer).
// r4: zero sub-fp16 quantization headroom. r6: no cooperative launch under capture.
#define OFF_SSRC    0u                        // NBUCK*CAP ints = 20 MB (gapped)
#define OFF_ROWINFO 20971520u                 // N u32 = 4 MB
#define OFF_CURSOR  25165824u                 // NBUCK ints
#define OFF_STATS   (25165824u + 4096u)       // 10*SS floats
#define OFF_XPAD    33554432u                 // N float4 = 16 MB
#define OFF_HA      50331648u                 // N*16 halves = 32 MB
#define OFF_HB      83886080u                 // N*16 halves = 32 MB
#define OFF_EBUF    50331648u                 // NBUCK*CAP int2 = 40 MB (aliases hA/hB; dead before layer1)
#define SS 384                                // stats slot stride (floats)

// ================= init: bucket cursors + stats zero =================
__global__ void k_init(int* __restrict__ cursor, float* __restrict__ stats){
  int t = threadIdx.x;
  cursor[t] = t * CAP;
  for(int i = t; i < 10*SS; i += 256) stats[i] = 0.0f;
}

// ============ pass B: bin edges into 256 buckets by dst>>12 ============
__global__ void k_bucket(const int* __restrict__ src, const int* __restrict__ dst,
                         int* __restrict__ cursor, int2* __restrict__ ebuf){
  __shared__ int hist[NBUCK];
  __shared__ int base[NBUCK];
  int t = threadIdx.x;
  hist[t] = 0;
  __syncthreads();
  int eb = blockIdx.x * 4096;
  int s[16], d[16], r[16];
#pragma unroll
  for(int k=0; k<16; k++){
    int e = eb + k*256 + t;
    s[k] = src[e];
    d[k] = dst[e];
    r[k] = atomicAdd(&hist[d[k] >> 12], 1);
  }
  __syncthreads();
  base[t] = atomicAdd(&cursor[t], hist[t]);
  __syncthreads();
#pragma unroll
  for(int k=0; k<16; k++){
    int b = d[k] >> 12;
    int pos = base[b] + r[k];
    if(pos < (b+1)*CAP)                 // capacity guard (never triggers for this data)
      ebuf[pos] = make_int2(s[k], d[k]);
  }
}

// ===== pass C: per-bucket counting sort -> rowinfo/ssrc =====
__global__ void k_csr(const int2* __restrict__ ebuf, const int* __restrict__ cursor,
                      int* __restrict__ ssrc, u32* __restrict__ rowinfo){
  __shared__ int hist[BNODES];
  __shared__ int part[256];
  int b = blockIdx.x, t = threadIdx.x;
  int cnt = cursor[b] - b*CAP;
  if(cnt > CAP) cnt = CAP;
  int ebase = b*CAP;
  for(int i=t; i<BNODES; i+=256) hist[i] = 0;
  __syncthreads();
  for(int i=t; i<cnt; i+=256){
    int2 e = ebuf[ebase + i];
    atomicAdd(&hist[e.y & (BNODES-1)], 1);
  }
  __syncthreads();
  int loc[16]; int sum = 0;
#pragma unroll
  for(int j=0; j<16; j++){ loc[j] = hist[t*16 + j]; sum += loc[j]; }
  part[t] = sum;
  __syncthreads();
#pragma unroll
  for(int off=1; off<256; off<<=1){
    int v = (t >= off) ? part[t-off] : 0;
    __syncthreads();
    part[t] += v;
    __syncthreads();
  }
  int run = part[t] - sum;   // exclusive prefix for this thread's 16 nodes
#pragma unroll
  for(int j=0; j<16; j++){
    int n = b*BNODES + t*16 + j;
    int deg = loc[j]; if(deg > 127) deg = 127;   // P(deg>127) ~ 0 for Poisson(4)
    rowinfo[n] = ((u32)(ebase + run) << 7) | (u32)deg;
    hist[t*16 + j] = run;
    run += loc[j];
  }
  __syncthreads();
  for(int i=t; i<cnt; i+=256){
    int2 e = ebuf[ebase + i];
    int pos = atomicAdd(&hist[e.y & (BNODES-1)], 1);
    ssrc[ebase + pos] = e.x;
  }
}

// ===== x prep: fp32 [N,3] -> padded float4 rows (1 request per layer-1 gather) =====
__global__ void k_xprep(const float* __restrict__ x, float4* __restrict__ xpad){
  int stride = gridDim.x*blockDim.x;
  for(int i = blockIdx.x*blockDim.x + threadIdx.x; i < NN; i += stride){
    float4 v;
    v.x = x[3*i];
    v.y = x[3*i+1];
    v.z = x[3*i+2];
    v.w = 0.0f;
    xpad[i] = v;
  }
}

// ================= stats helpers =================
template<int NF>
__device__ __forceinline__ void stats_flush(float* ssum, float* ssq,
                                            float* __restrict__ stats_out){
  __shared__ float sred[2*NF];
#pragma unroll
  for(int f=0; f<NF; f++){
    float a = ssum[f], b = ssq[f];
#pragma unroll
    for(int off=1; off<64; off<<=1){
      a += __shfl_xor(a, off, 64);
      b += __shfl_xor(b, off, 64);
    }
    ssum[f] = a; ssq[f] = b;
  }
  if(threadIdx.x < 2*NF) sred[threadIdx.x] = 0.0f;
  __syncthreads();
  if((threadIdx.x & 63) == 0){
#pragma unroll
    for(int f=0; f<NF; f++){
      atomicAdd(&sred[f],      ssum[f]);
      atomicAdd(&sred[NF + f], ssq[f]);
    }
  }
  __syncthreads();
  if(threadIdx.x < 2*NF)
    atomicAdd(&stats_out[threadIdx.x * 16], sred[threadIdx.x]);  // 64B-spread counters
}

// pair variant: even lanes hold features 0..7 in slots 0..7; odd lanes hold
// features 8..11 in slots 0..3 (4..7 are zeros). Butterfly over same-parity
// lanes only (xor offsets 2..32), then lanes 0/1 of each wave flush.
__device__ __forceinline__ void stats_flush_pair(float* ssum, float* ssq,
                                                 float* __restrict__ stats_out){
  __shared__ float sred[24];
#pragma unroll
  for(int f=0; f<8; f++){
    float a = ssum[f], b = ssq[f];
#pragma unroll
    for(int off=2; off<64; off<<=1){
      a += __shfl_xor(a, off, 64);
      b += __shfl_xor(b, off, 64);
    }
    ssum[f] = a; ssq[f] = b;
  }
  if(threadIdx.x < 24) sred[threadIdx.x] = 0.0f;
  __syncthreads();
  if((threadIdx.x & 63) < 2){
    int base = (threadIdx.x & 1) * 8;
#pragma unroll
    for(int f=0; f<8; f++){
      int fg = base + f;
      if(fg < 12){
        atomicAdd(&sred[fg],      ssum[f]);
        atomicAdd(&sred[12 + fg], ssq[f]);
      }
    }
  }
  __syncthreads();
  if(threadIdx.x < 24)
    atomicAdd(&stats_out[threadIdx.x * 16], sred[threadIdx.x]);
}

__device__ __forceinline__ void store_row16(_Float16* __restrict__ hout, int i,
                                            const float* ov){
  half8 o0, o1;
#pragma unroll
  for(int j=0; j<8; j++) o0[j] = (_Float16)ov[j];
#pragma unroll
  for(int j=0; j<4; j++) o1[j] = (_Float16)ov[8+j];
  o1[4]=(_Float16)0.f; o1[5]=(_Float16)0.f; o1[6]=(_Float16)0.f; o1[7]=(_Float16)0.f;
  half8* op = (half8*)(hout + 16*i);
  op[0] = o0; op[1] = o1;
}

// ================= conv layer 1: xpad[N] float4 -> h[N,16] fp16 =================
__global__ void k_layer1(const float4* __restrict__ xpad,
                         const u32* __restrict__ rowinfo,
                         const int* __restrict__ ssrc,
                         const float* __restrict__ Wl1, const float* __restrict__ Wr1,
                         const float* __restrict__ b1,
                         _Float16* __restrict__ hout, float* __restrict__ stats_out){
  float ssum[12], ssq[12];
#pragma unroll
  for(int f=0; f<12; f++){ ssum[f]=0.f; ssq[f]=0.f; }
  int stride = gridDim.x*blockDim.x;
  for(int i = blockIdx.x*blockDim.x + threadIdx.x; i < NN; i += stride){
    u32 ri = rowinfo[i];
    int st = (int)(ri >> 7);
    int deg = (int)(ri & 127u);
    int en = st + deg;
    float4 xr = xpad[i];                     // root load issued early (indep line)
    float a0=0.f, a1=0.f, a2=0.f;
    int p = st;
    for(; p+4 <= en; p += 4){
      int s0=ssrc[p], s1=ssrc[p+1], s2=ssrc[p+2], s3=ssrc[p+3];
      float4 u = xpad[s0];
      float4 v = xpad[s1];
      float4 w = xpad[s2];
      float4 y = xpad[s3];
      a0 += u.x+v.x+w.x+y.x; a1 += u.y+v.y+w.y+y.y; a2 += u.z+v.z+w.z+y.z;
    }
    for(; p<en; p++){
      float4 u = xpad[ssrc[p]];
      a0 += u.x; a1 += u.y; a2 += u.z;
    }
    float inv = (deg > 0) ? 1.0f/(float)deg : 0.0f;
    a0 *= inv; a1 *= inv; a2 *= inv;
    float x0 = xr.x, x1 = xr.y, x2 = xr.z;
    float ov[12];
#pragma unroll
    for(int f=0; f<12; f++){
      float o = b1[f]
              + Wl1[3*f]*a0 + Wl1[3*f+1]*a1 + Wl1[3*f+2]*a2
              + Wr1[3*f]*x0 + Wr1[3*f+1]*x1 + Wr1[3*f+2]*x2;
      o = fmaxf(o, 0.0f);
      ov[f] = o; ssum[f] += o; ssq[f] += o*o;
    }
    store_row16(hout, i, ov);
  }
  stats_flush<12>(ssum, ssq, stats_out);
}

// ========== conv layers 2..8, LANE-PAIR version ==========
// Lanes 2j (half=0: features 0..7) and 2j+1 (half=1: features 8..11 + pad)
// process the SAME node in lockstep; each gather instruction loads the two
// 16B halves of one 32B row at consecutive addresses -> ONE coalesced
// transaction per edge. Per-feature fp32 summation order identical to the
// single-thread version -> bit-identical numerics.
template<bool STATS>
__global__ void k_layerk(const _Float16* __restrict__ hin,
                         const u32* __restrict__ rowinfo,
                         const int* __restrict__ ssrc,
                         const float* __restrict__ Wl, const float* __restrict__ Wr,
                         const float* __restrict__ bias,
                         const float* __restrict__ bng, const float* __restrict__ bnb,
                         const float* __restrict__ stats_in,
                         _Float16* __restrict__ hout, float* __restrict__ stats_out){
  float sc[12], sh[12];
#pragma unroll
  for(int f=0; f<12; f++){
    float m = stats_in[f*16]      * (1.0f/NN);
    float v = stats_in[(12+f)*16] * (1.0f/NN) - m*m;
    float is = rsqrtf(v + BN_EPS);
    sc[f] = bng[f]*is;
    sh[f] = bnb[f] - m*sc[f];
  }
  float ssum[8], ssq[8];
  if(STATS){
#pragma unroll
    for(int f=0; f<8; f++){ ssum[f]=0.f; ssq[f]=0.f; }
  }
  int half = threadIdx.x & 1;
  int pair_stride = (gridDim.x*blockDim.x) >> 1;
  for(int i = (blockIdx.x*blockDim.x + threadIdx.x) >> 1; i < NN; i += pair_stride){
    u32 ri = rowinfo[i];                     // same addr in pair -> broadcast
    int st = (int)(ri >> 7);
    int deg = (int)(ri & 127u);
    int en = st + deg;
    const half8* hrow = (const half8*)(hin + 16*i);
    half8 r = hrow[half];                    // pair-coalesced 32B root read
    float s[8];
#pragma unroll
    for(int k=0; k<8; k++) s[k]=0.f;
    int p = st;
    for(; p+4 <= en; p += 4){
      int s0=ssrc[p], s1=ssrc[p+1], s2=ssrc[p+2], s3=ssrc[p+3];   // same addrs in pair
      half8 a0 = ((const half8*)(hin + 16*s0))[half];   // 1 coalesced 32B txn/edge
      half8 a1 = ((const half8*)(hin + 16*s1))[half];
      half8 a2 = ((const half8*)(hin + 16*s2))[half];
      half8 a3 = ((const half8*)(hin + 16*s3))[half];
#pragma unroll
      for(int k=0; k<8; k++)
        s[k] += (float)a0[k] + (float)a1[k] + (float)a2[k] + (float)a3[k];
    }
    for(; p<en; p++){
      half8 q = ((const half8*)(hin + 16*ssrc[p]))[half];
#pragma unroll
      for(int k=0; k<8; k++) s[k] += (float)q[k];
    }
    // exchange with partner lane: sums + root features
    float hi[8], so[8], hio[8];
#pragma unroll
    for(int k=0; k<8; k++) hi[k] = (float)r[k];
#pragma unroll
    for(int k=0; k<8; k++){ so[k] = __shfl_xor(s[k], 1, 64); hio[k] = __shfl_xor(hi[k], 1, 64); }
    // assemble full 12-feature vectors (even: s=0..7, so[0..3]=8..11; odd swapped)
    float aggf[12], hif[12];
#pragma unroll
    for(int k=0; k<8; k++){ aggf[k] = half ? so[k] : s[k];  hif[k] = half ? hio[k] : hi[k]; }
#pragma unroll
    for(int k=0; k<4; k++){ aggf[8+k] = half ? s[k] : so[k]; hif[8+k] = half ? hi[k] : hio[k]; }
    float inv   = (deg > 0) ? 1.0f/(float)deg : 0.0f;
    float zmask = (deg > 0) ? 1.0f : 0.0f;
    float aggn[12], hn[12];
#pragma unroll
    for(int k=0; k<12; k++){
      aggn[k] = (aggf[k]*inv*sc[k] + sh[k]) * zmask;  // mean-of-BN'd == BN-of-mean
      hn[k]   = hif[k]*sc[k] + sh[k];
    }
    // outputs: even lane computes features 0..7, odd 8..11 (slots 4..7 zero=pad)
    float ov[8];
#pragma unroll
    for(int f=0; f<8; f++){
      int fg = half*8 + f;
      float o = 0.0f;
      if(fg < 12){
        o = bias[fg];
#pragma unroll
        for(int k=0; k<12; k++) o += Wl[12*fg+k]*aggn[k];
#pragma unroll
        for(int k=0; k<12; k++) o += Wr[12*fg+k]*hn[k];
        o = fmaxf(o, 0.0f);
      }
      ov[f] = o;
      if(STATS){ ssum[f] += o; ssq[f] += o*o; }
    }
    half8 og;
#pragma unroll
    for(int j=0; j<8; j++) og[j] = (_Float16)ov[j];
    ((half8*)(hout + 16*i))[half] = og;      // pair-coalesced 32B store
  }
  if(STATS) stats_flush_pair(ssum, ssq, stats_out);
}

// ========== head linear on [2N,6] stored as padded fp16 [N,16] ==========
// one thread = one padded row = two consecutive [2N,6] sub-rows
template<bool FIRST>
__global__ void k_head(const _Float16* __restrict__ zin,
                       const float* __restrict__ W, const float* __restrict__ bv,
                       const float* __restrict__ g6, const float* __restrict__ b6,
                       const float* __restrict__ stats_in,
                       _Float16* __restrict__ zout, float* __restrict__ stats_out){
  float sc[6], sh[6];
  if(!FIRST){
#pragma unroll
    for(int k=0; k<6; k++){
      float m = stats_in[k*16]     * (1.0f/(2.0f*NN));
      float v = stats_in[(6+k)*16] * (1.0f/(2.0f*NN)) - m*m;
      float is = rsqrtf(v + BN_EPS);
      sc[k] = g6[k]*is;
      sh[k] = b6[k] - m*sc[k];
    }
  }
  float ssum[6], ssq[6];
#pragma unroll
  for(int f=0; f<6; f++){ ssum[f]=0.f; ssq[f]=0.f; }
  int stride = gridDim.x*blockDim.x;
  for(int i = blockIdx.x*blockDim.x + threadIdx.x; i < NN; i += stride){
    const half8* zp = (const half8*)(zin + 16*i);
    half8 a = zp[0], b = zp[1];
    float t0[6] = {(float)a[0],(float)a[1],(float)a[2],(float)a[3],(float)a[4],(float)a[5]};
    float t1[6] = {(float)a[6],(float)a[7],(float)b[0],(float)b[1],(float)b[2],(float)b[3]};
    if(!FIRST){
#pragma unroll
      for(int k=0; k<6; k++){
        t0[k] = fmaxf(t0[k]*sc[k] + sh[k], 0.0f);
        t1[k] = fmaxf(t1[k]*sc[k] + sh[k], 0.0f);
      }
    }
    float ov[12];
#pragma unroll
    for(int f=0; f<6; f++){
      float o0 = bv[f], o1 = bv[f];
#pragma unroll
      for(int k=0; k<6; k++){ o0 += W[6*f+k]*t0[k]; o1 += W[6*f+k]*t1[k]; }
      ov[f] = o0; ov[6+f] = o1;
      ssum[f] += o0 + o1; ssq[f] += o0*o0 + o1*o1;
    }
    store_row16(zout, i, ov);
  }
  stats_flush<6>(ssum, ssq, stats_out);
}

// ========== final: BN+ReLU + Linear(6,1) + sigmoid; one thread = 2 outputs ==========
__global__ void k_out(const _Float16* __restrict__ zin,
                      const float* __restrict__ g6, const float* __restrict__ b6,
                      const float* __restrict__ stats_in,
                      const float* __restrict__ outW, const float* __restrict__ outb,
                      float* __restrict__ out){
  float sc[6], sh[6], w[6];
#pragma unroll
  for(int k=0; k<6; k++){
    float m = stats_in[k*16]     * (1.0f/(2.0f*NN));
    float v = stats_in[(6+k)*16] * (1.0f/(2.0f*NN)) - m*m;
    float is = rsqrtf(v + BN_EPS);
    sc[k] = g6[k]*is;
    sh[k] = b6[k] - m*sc[k];
    w[k] = outW[k];
  }
  float ob = outb[0];
  int stride = gridDim.x*blockDim.x;
  for(int i = blockIdx.x*blockDim.x + threadIdx.x; i < NN; i += stride){
    const half8* zp = (const half8*)(zin + 16*i);
    half8 a = zp[0], b = zp[1];
    float t0[6] = {(float)a[0],(float)a[1],(float)a[2],(float)a[3],(float)a[4],(float)a[5]};
    float t1[6] = {(float)a[6],(float)a[7],(float)b[0],(float)b[1],(float)b[2],(float)b[3]};
    float o0 = ob, o1 = ob;
#pragma unroll
    for(int k=0; k<6; k++){
      o0 += w[k] * fmaxf(t0[k]*sc[k] + sh[k], 0.0f);
      o1 += w[k] * fmaxf(t1[k]*sc[k] + sh[k], 0.0f);
    }
    float2 r;
    r.x = 1.0f / (1.0f + expf(-o0));
    r.y = 1.0f / (1.0f + expf(-o1));
    ((float2*)out)[i] = r;
  }
}

extern "C" void kernel_launch(void* const* d_in, const int* in_sizes, int n_in,
                              void* d_out, int out_size, void* d_ws, size_t ws_size,
                              hipStream_t stream){
  const float* x    = (const float*)d_in[0];
  const int*   ei   = (const int*)  d_in[1];
  const float* Wl1  = (const float*)d_in[2];
  const float* Wr1  = (const float*)d_in[3];
  const float* b1   = (const float*)d_in[4];
  const float* Wl   = (const float*)d_in[5];
  const float* Wr   = (const float*)d_in[6];
  const float* bb   = (const float*)d_in[7];
  const float* bng  = (const float*)d_in[8];
  const float* bnb  = (const float*)d_in[9];
  const float* linW = (const float*)d_in[10];
  const float* linb = (const float*)d_in[11];
  const float* bn6g = (const float*)d_in[12];
  const float* bn6b = (const float*)d_in[13];
  const float* outW = (const float*)d_in[14];
  const float* outb = (const float*)d_in[15];
  float* out = (float*)d_out;

  char* ws = (char*)d_ws;
  int*      ssrc    = (int*)     (ws + OFF_SSRC);
  u32*      rowinfo = (u32*)     (ws + OFF_ROWINFO);
  int*      cursor  = (int*)     (ws + OFF_CURSOR);
  float*    stats   = (float*)   (ws + OFF_STATS);
  float4*   xpad    = (float4*)  (ws + OFF_XPAD);
  _Float16* hA      = (_Float16*)(ws + OFF_HA);
  _Float16* hB      = (_Float16*)(ws + OFF_HB);
  int2*     ebuf    = (int2*)    (ws + OFF_EBUF);   // aliases hA/hB; dead after k_csr

  const int* srcp = ei;
  const int* dstp = ei + EE;

  k_init  <<<1,    256, 0, stream>>>(cursor, stats);
  k_bucket<<<1024, 256, 0, stream>>>(srcp, dstp, cursor, ebuf);
  k_csr   <<<NBUCK,256, 0, stream>>>(ebuf, cursor, ssrc, rowinfo);
  k_xprep <<<1024, 256, 0, stream>>>(x, xpad);

  // conv1 (stats -> slot 0): one float4 request per edge
  k_layer1<<<NBLK, TPB, 0, stream>>>(xpad, rowinfo, ssrc, Wl1, Wr1, b1, hA, stats);

  // conv2..conv8 (lane-pair gathers)
  _Float16* hi = hA; _Float16* ho = hB;
  for(int l=0; l<7; l++){
    const float* st_in = stats + l*SS;
    float* st_out      = stats + (l+1)*SS;
    if(l < 6)
      k_layerk<true><<<NBLK, TPB, 0, stream>>>(hi, rowinfo, ssrc,
        Wl + 144*l, Wr + 144*l, bb + 12*l, bng + 12*l, bnb + 12*l, st_in, ho, st_out);
    else
      k_layerk<false><<<NBLK, TPB, 0, stream>>>(hi, rowinfo, ssrc,
        Wl + 144*l, Wr + 144*l, bb + 12*l, bng + 12*l, bnb + 12*l, st_in, ho, st_out);
    _Float16* t = hi; hi = ho; ho = t;
  }
  // hi = conv8 output, padded fp16 rows; head views each row as two [2N,6] sub-rows

  // head: z1 (stats slot 7)
  k_head<true> <<<NBLK, TPB, 0, stream>>>(hi, linW, linb, bn6g, bn6b,
                                          stats + 7*SS, ho, stats + 7*SS);
  { _Float16* t = hi; hi = ho; ho = t; }
  // z2 (slot 8)
  k_head<false><<<NBLK, TPB, 0, stream>>>(hi, linW, linb, bn6g, bn6b,
                                          stats + 7*SS, ho, stats + 8*SS);
  { _Float16* t = hi; hi = ho; ho = t; }
  // z3 (slot 9)
  k_head<false><<<NBLK, TPB, 0, stream>>>(hi, linW, linb, bn6g, bn6b,
                                          stats + 8*SS, ho, stats + 9*SS);
  { _Float16* t = hi; hi = ho; ho = t; }
  // final
  k_out<<<NBLK, TPB, 0, stream>>>(hi, bn6g, bn6b, stats + 9*SS, outW, outb, out);
}

// Round 9
// 1313.110 us; speedup vs baseline: 1.6549x; 1.6549x over previous
//
#include <hip/hip_runtime.h>
#include <math.h>

#define NN 1048576
#define EE 4194304
#define TPB 256
#define NBLK 2048
#define NBUCK 256
#define BNODES 4096          // nodes per bucket (NN / NBUCK)
#define CAP 20480            // bucket edge capacity (mean 16384, sigma~128)
constexpr float BN_EPS = 1e-5f;

typedef _Float16 half8  __attribute__((ext_vector_type(8)));
typedef unsigned int u32;
typedef unsigned long long u64;

// ---- workspace layout (bytes) ----
// Request-rate model (r0-r8): k_layerk time ~ 8M random 16B requests / 63G/s.
// Per-lane b128 is the widest load -> 2 reqs per 32B row is an ISA floor.
// Falsified alternatives: row-split (r1, 2x lines), extra MLP (r2), scatter
// (r3, RFO), sub-fp16 (r4, no accuracy headroom), coop-launch fusion (r6,
// silent no-op under graph capture), lane-pair coalescing (r8, 2.3x traffic +
// divergent weight loads). Tail-only win: conv8 output + head chain use 24B
// packed rows (streaming only, never gathered) -- verified components from r3.
#define OFF_SSRC    0u                        // NBUCK*CAP ints = 20 MB (gapped)
#define OFF_ROWINFO 20971520u                 // N u32 = 4 MB
#define OFF_CURSOR  25165824u                 // NBUCK ints
#define OFF_STATS   (25165824u + 4096u)       // 10*SS floats
#define OFF_XPAD    33554432u                 // N float4 = 16 MB
#define OFF_HA      50331648u                 // N*16 halves = 32 MB
#define OFF_HB      83886080u                 // N*16 halves = 32 MB
#define OFF_EBUF    50331648u                 // NBUCK*CAP int2 = 40 MB (aliases hA/hB; dead before layer1)
#define SS 384                                // stats slot stride (floats)

// ================= init: bucket cursors + stats zero =================
__global__ void k_init(int* __restrict__ cursor, float* __restrict__ stats){
  int t = threadIdx.x;
  cursor[t] = t * CAP;
  for(int i = t; i < 10*SS; i += 256) stats[i] = 0.0f;
}

// ============ pass B: bin edges into 256 buckets by dst>>12 ============
__global__ void k_bucket(const int* __restrict__ src, const int* __restrict__ dst,
                         int* __restrict__ cursor, int2* __restrict__ ebuf){
  __shared__ int hist[NBUCK];
  __shared__ int base[NBUCK];
  int t = threadIdx.x;
  hist[t] = 0;
  __syncthreads();
  int eb = blockIdx.x * 4096;
  int s[16], d[16], r[16];
#pragma unroll
  for(int k=0; k<16; k++){
    int e = eb + k*256 + t;
    s[k] = src[e];
    d[k] = dst[e];
    r[k] = atomicAdd(&hist[d[k] >> 12], 1);
  }
  __syncthreads();
  base[t] = atomicAdd(&cursor[t], hist[t]);
  __syncthreads();
#pragma unroll
  for(int k=0; k<16; k++){
    int b = d[k] >> 12;
    int pos = base[b] + r[k];
    if(pos < (b+1)*CAP)                 // capacity guard (never triggers for this data)
      ebuf[pos] = make_int2(s[k], d[k]);
  }
}

// ===== pass C: per-bucket counting sort -> rowinfo/ssrc =====
__global__ void k_csr(const int2* __restrict__ ebuf, const int* __restrict__ cursor,
                      int* __restrict__ ssrc, u32* __restrict__ rowinfo){
  __shared__ int hist[BNODES];
  __shared__ int part[256];
  int b = blockIdx.x, t = threadIdx.x;
  int cnt = cursor[b] - b*CAP;
  if(cnt > CAP) cnt = CAP;
  int ebase = b*CAP;
  for(int i=t; i<BNODES; i+=256) hist[i] = 0;
  __syncthreads();
  for(int i=t; i<cnt; i+=256){
    int2 e = ebuf[ebase + i];
    atomicAdd(&hist[e.y & (BNODES-1)], 1);
  }
  __syncthreads();
  int loc[16]; int sum = 0;
#pragma unroll
  for(int j=0; j<16; j++){ loc[j] = hist[t*16 + j]; sum += loc[j]; }
  part[t] = sum;
  __syncthreads();
#pragma unroll
  for(int off=1; off<256; off<<=1){
    int v = (t >= off) ? part[t-off] : 0;
    __syncthreads();
    part[t] += v;
    __syncthreads();
  }
  int run = part[t] - sum;   // exclusive prefix for this thread's 16 nodes
#pragma unroll
  for(int j=0; j<16; j++){
    int n = b*BNODES + t*16 + j;
    int deg = loc[j]; if(deg > 127) deg = 127;   // P(deg>127) ~ 0 for Poisson(4)
    rowinfo[n] = ((u32)(ebase + run) << 7) | (u32)deg;
    hist[t*16 + j] = run;
    run += loc[j];
  }
  __syncthreads();
  for(int i=t; i<cnt; i+=256){
    int2 e = ebuf[ebase + i];
    int pos = atomicAdd(&hist[e.y & (BNODES-1)], 1);
    ssrc[ebase + pos] = e.x;
  }
}

// ===== x prep: fp32 [N,3] -> padded float4 rows (1 request per layer-1 gather) =====
__global__ void k_xprep(const float* __restrict__ x, float4* __restrict__ xpad){
  int stride = gridDim.x*blockDim.x;
  for(int i = blockIdx.x*blockDim.x + threadIdx.x; i < NN; i += stride){
    float4 v;
    v.x = x[3*i];
    v.y = x[3*i+1];
    v.z = x[3*i+2];
    v.w = 0.0f;
    xpad[i] = v;
  }
}

// ================= stats helpers =================
template<int NF>
__device__ __forceinline__ void stats_flush(float* ssum, float* ssq,
                                            float* __restrict__ stats_out){
  __shared__ float sred[2*NF];
#pragma unroll
  for(int f=0; f<NF; f++){
    float a = ssum[f], b = ssq[f];
#pragma unroll
    for(int off=1; off<64; off<<=1){
      a += __shfl_xor(a, off, 64);
      b += __shfl_xor(b, off, 64);
    }
    ssum[f] = a; ssq[f] = b;
  }
  if(threadIdx.x < 2*NF) sred[threadIdx.x] = 0.0f;
  __syncthreads();
  if((threadIdx.x & 63) == 0){
#pragma unroll
    for(int f=0; f<NF; f++){
      atomicAdd(&sred[f],      ssum[f]);
      atomicAdd(&sred[NF + f], ssq[f]);
    }
  }
  __syncthreads();
  if(threadIdx.x < 2*NF)
    atomicAdd(&stats_out[threadIdx.x * 16], sred[threadIdx.x]);  // 64B-spread counters
}

__device__ __forceinline__ void store_row16(_Float16* __restrict__ hout, int i,
                                            const float* ov){
  half8 o0, o1;
#pragma unroll
  for(int j=0; j<8; j++) o0[j] = (_Float16)ov[j];
#pragma unroll
  for(int j=0; j<4; j++) o1[j] = (_Float16)ov[8+j];
  o1[4]=(_Float16)0.f; o1[5]=(_Float16)0.f; o1[6]=(_Float16)0.f; o1[7]=(_Float16)0.f;
  half8* op = (half8*)(hout + 16*i);
  op[0] = o0; op[1] = o1;
}

// ---- 24B packed rows (fp16x12 as 3x u64) for streaming-only tail (verified r3) ----
union U4H { u64 u; _Float16 h[4]; };

__device__ __forceinline__ u64 pack4(const float* v){
  U4H x;
  x.h[0]=(_Float16)v[0]; x.h[1]=(_Float16)v[1];
  x.h[2]=(_Float16)v[2]; x.h[3]=(_Float16)v[3];
  return x.u;
}
__device__ __forceinline__ void unpack4(u64 u, float* v){
  U4H x; x.u = u;
  v[0]=(float)x.h[0]; v[1]=(float)x.h[1]; v[2]=(float)x.h[2]; v[3]=(float)x.h[3];
}
__device__ __forceinline__ void store_row12(u64* __restrict__ h, int i, const float* ov){
  u64* p = h + (size_t)i*3;
  p[0] = pack4(ov); p[1] = pack4(ov+4); p[2] = pack4(ov+8);
}
__device__ __forceinline__ void load_row12(const u64* __restrict__ h, int i, float* v){
  const u64* p = h + (size_t)i*3;
  unpack4(p[0], v); unpack4(p[1], v+4); unpack4(p[2], v+8);
}

// ================= conv layer 1: xpad[N] float4 -> h[N,16] fp16 =================
__global__ void k_layer1(const float4* __restrict__ xpad,
                         const u32* __restrict__ rowinfo,
                         const int* __restrict__ ssrc,
                         const float* __restrict__ Wl1, const float* __restrict__ Wr1,
                         const float* __restrict__ b1,
                         _Float16* __restrict__ hout, float* __restrict__ stats_out){
  float ssum[12], ssq[12];
#pragma unroll
  for(int f=0; f<12; f++){ ssum[f]=0.f; ssq[f]=0.f; }
  int stride = gridDim.x*blockDim.x;
  for(int i = blockIdx.x*blockDim.x + threadIdx.x; i < NN; i += stride){
    u32 ri = rowinfo[i];
    int st = (int)(ri >> 7);
    int deg = (int)(ri & 127u);
    int en = st + deg;
    float4 xr = xpad[i];                     // root load issued early (indep line)
    float a0=0.f, a1=0.f, a2=0.f;
    int p = st;
    for(; p+4 <= en; p += 4){
      int s0=ssrc[p], s1=ssrc[p+1], s2=ssrc[p+2], s3=ssrc[p+3];
      float4 u = xpad[s0];
      float4 v = xpad[s1];
      float4 w = xpad[s2];
      float4 y = xpad[s3];
      a0 += u.x+v.x+w.x+y.x; a1 += u.y+v.y+w.y+y.y; a2 += u.z+v.z+w.z+y.z;
    }
    for(; p<en; p++){
      float4 u = xpad[ssrc[p]];
      a0 += u.x; a1 += u.y; a2 += u.z;
    }
    float inv = (deg > 0) ? 1.0f/(float)deg : 0.0f;
    a0 *= inv; a1 *= inv; a2 *= inv;
    float x0 = xr.x, x1 = xr.y, x2 = xr.z;
    float ov[12];
#pragma unroll
    for(int f=0; f<12; f++){
      float o = b1[f]
              + Wl1[3*f]*a0 + Wl1[3*f+1]*a1 + Wl1[3*f+2]*a2
              + Wr1[3*f]*x0 + Wr1[3*f+1]*x1 + Wr1[3*f+2]*x2;
      o = fmaxf(o, 0.0f);
      ov[f] = o; ssum[f] += o; ssq[f] += o*o;
    }
    store_row16(hout, i, ov);
  }
  stats_flush<12>(ssum, ssq, stats_out);
}

// ========== conv layers 2..8: BN folded + SAGE, fp16 [N,16] -> fp16 ==========
// PACK24: last conv layer stores 24B packed rows (consumed only by streaming head).
template<bool STATS, bool PACK24>
__global__ void k_layerk(const _Float16* __restrict__ hin,
                         const u32* __restrict__ rowinfo,
                         const int* __restrict__ ssrc,
                         const float* __restrict__ Wl, const float* __restrict__ Wr,
                         const float* __restrict__ bias,
                         const float* __restrict__ bng, const float* __restrict__ bnb,
                         const float* __restrict__ stats_in,
                         _Float16* __restrict__ hout, float* __restrict__ stats_out){
  float sc[12], sh[12];
#pragma unroll
  for(int f=0; f<12; f++){
    float m = stats_in[f*16]      * (1.0f/NN);
    float v = stats_in[(12+f)*16] * (1.0f/NN) - m*m;
    float is = rsqrtf(v + BN_EPS);
    sc[f] = bng[f]*is;
    sh[f] = bnb[f] - m*sc[f];
  }
  float ssum[12], ssq[12];
  if(STATS){
#pragma unroll
    for(int f=0; f<12; f++){ ssum[f]=0.f; ssq[f]=0.f; }
  }
  int stride = gridDim.x*blockDim.x;
  for(int i = blockIdx.x*blockDim.x + threadIdx.x; i < NN; i += stride){
    u32 ri = rowinfo[i];
    int st = (int)(ri >> 7);
    int deg = (int)(ri & 127u);
    int en = st + deg;
    const half8* hp = (const half8*)(hin + 16*i);
    half8 r0 = hp[0], r1 = hp[1];            // root row issued early (indep line)
    float s[12];
#pragma unroll
    for(int k=0; k<12; k++) s[k]=0.f;
    int p = st;
    for(; p+4 <= en; p += 4){
      int s0=ssrc[p], s1=ssrc[p+1], s2=ssrc[p+2], s3=ssrc[p+3];
      const half8* h0 = (const half8*)(hin + 16*s0);
      const half8* h1 = (const half8*)(hin + 16*s1);
      const half8* h2 = (const half8*)(hin + 16*s2);
      const half8* h3 = (const half8*)(hin + 16*s3);
      half8 a0=h0[0], b0=h0[1];
      half8 a1=h1[0], b1=h1[1];
      half8 a2=h2[0], b2=h2[1];
      half8 a3=h3[0], b3=h3[1];
#pragma unroll
      for(int k=0; k<8; k++)
        s[k] += (float)a0[k] + (float)a1[k] + (float)a2[k] + (float)a3[k];
#pragma unroll
      for(int k=0; k<4; k++)
        s[8+k] += (float)b0[k] + (float)b1[k] + (float)b2[k] + (float)b3[k];
    }
    for(; p<en; p++){
      int sid = ssrc[p];
      const half8* hq = (const half8*)(hin + 16*sid);
      half8 q0 = hq[0], q1 = hq[1];
#pragma unroll
      for(int k=0; k<8; k++) s[k] += (float)q0[k];
#pragma unroll
      for(int k=0; k<4; k++) s[8+k] += (float)q1[k];
    }
    float inv   = (deg > 0) ? 1.0f/(float)deg : 0.0f;
    float zmask = (deg > 0) ? 1.0f : 0.0f;
    float hi[12];
#pragma unroll
    for(int k=0; k<8; k++) hi[k] = (float)r0[k];
#pragma unroll
    for(int k=0; k<4; k++) hi[8+k] = (float)r1[k];
    float aggn[12], hn[12];
#pragma unroll
    for(int k=0; k<12; k++){
      aggn[k] = (s[k]*inv*sc[k] + sh[k]) * zmask;  // mean-of-BN'd == BN-of-mean; deg=0 -> 0
      hn[k]   = hi[k]*sc[k] + sh[k];
    }
    float ov[12];
#pragma unroll
    for(int f=0; f<12; f++){
      float o = bias[f];
#pragma unroll
      for(int k=0; k<12; k++) o += Wl[12*f+k]*aggn[k];
#pragma unroll
      for(int k=0; k<12; k++) o += Wr[12*f+k]*hn[k];
      o = fmaxf(o, 0.0f);
      ov[f] = o;
      if(STATS){ ssum[f] += o; ssq[f] += o*o; }
    }
    if(PACK24) store_row12((u64*)hout, i, ov);
    else       store_row16(hout, i, ov);
  }
  if(STATS) stats_flush<12>(ssum, ssq, stats_out);
}

// ========== head linear on [2N,6] stored as packed 24B rows (verified r3) ==========
template<bool FIRST>
__global__ void k_head12(const u64* __restrict__ zin,
                         const float* __restrict__ W, const float* __restrict__ bv,
                         const float* __restrict__ g6, const float* __restrict__ b6,
                         const float* __restrict__ stats_in,
                         u64* __restrict__ zout, float* __restrict__ stats_out){
  float sc[6], sh[6];
  if(!FIRST){
#pragma unroll
    for(int k=0; k<6; k++){
      float m = stats_in[k*16]     * (1.0f/(2.0f*NN));
      float v = stats_in[(6+k)*16] * (1.0f/(2.0f*NN)) - m*m;
      float is = rsqrtf(v + BN_EPS);
      sc[k] = g6[k]*is;
      sh[k] = b6[k] - m*sc[k];
    }
  }
  float ssum[6], ssq[6];
#pragma unroll
  for(int f=0; f<6; f++){ ssum[f]=0.f; ssq[f]=0.f; }
  int stride = gridDim.x*blockDim.x;
  for(int i = blockIdx.x*blockDim.x + threadIdx.x; i < NN; i += stride){
    float t[12];
    load_row12(zin, i, t);
    float* t0 = t; float* t1 = t + 6;
    if(!FIRST){
#pragma unroll
      for(int k=0; k<6; k++){
        t0[k] = fmaxf(t0[k]*sc[k] + sh[k], 0.0f);
        t1[k] = fmaxf(t1[k]*sc[k] + sh[k], 0.0f);
      }
    }
    float ov[12];
#pragma unroll
    for(int f=0; f<6; f++){
      float o0 = bv[f], o1 = bv[f];
#pragma unroll
      for(int k=0; k<6; k++){ o0 += W[6*f+k]*t0[k]; o1 += W[6*f+k]*t1[k]; }
      ov[f] = o0; ov[6+f] = o1;
      ssum[f] += o0 + o1; ssq[f] += o0*o0 + o1*o1;
    }
    store_row12(zout, i, ov);
  }
  stats_flush<6>(ssum, ssq, stats_out);
}

// ========== final: BN+ReLU + Linear(6,1) + sigmoid; one thread = 2 outputs ==========
__global__ void k_out12(const u64* __restrict__ zin,
                        const float* __restrict__ g6, const float* __restrict__ b6,
                        const float* __restrict__ stats_in,
                        const float* __restrict__ outW, const float* __restrict__ outb,
                        float* __restrict__ out){
  float sc[6], sh[6], w[6];
#pragma unroll
  for(int k=0; k<6; k++){
    float m = stats_in[k*16]     * (1.0f/(2.0f*NN));
    float v = stats_in[(6+k)*16] * (1.0f/(2.0f*NN)) - m*m;
    float is = rsqrtf(v + BN_EPS);
    sc[k] = g6[k]*is;
    sh[k] = b6[k] - m*sc[k];
    w[k] = outW[k];
  }
  float ob = outb[0];
  int stride = gridDim.x*blockDim.x;
  for(int i = blockIdx.x*blockDim.x + threadIdx.x; i < NN; i += stride){
    float t[12];
    load_row12(zin, i, t);
    float o0 = ob, o1 = ob;
#pragma unroll
    for(int k=0; k<6; k++){
      o0 += w[k] * fmaxf(t[k]*sc[k] + sh[k], 0.0f);
      o1 += w[k] * fmaxf(t[6+k]*sc[k] + sh[k], 0.0f);
    }
    float2 r;
    r.x = 1.0f / (1.0f + expf(-o0));
    r.y = 1.0f / (1.0f + expf(-o1));
    ((float2*)out)[i] = r;
  }
}

extern "C" void kernel_launch(void* const* d_in, const int* in_sizes, int n_in,
                              void* d_out, int out_size, void* d_ws, size_t ws_size,
                              hipStream_t stream){
  const float* x    = (const float*)d_in[0];
  const int*   ei   = (const int*)  d_in[1];
  const float* Wl1  = (const float*)d_in[2];
  const float* Wr1  = (const float*)d_in[3];
  const float* b1   = (const float*)d_in[4];
  const float* Wl   = (const float*)d_in[5];
  const float* Wr   = (const float*)d_in[6];
  const float* bb   = (const float*)d_in[7];
  const float* bng  = (const float*)d_in[8];
  const float* bnb  = (const float*)d_in[9];
  const float* linW = (const float*)d_in[10];
  const float* linb = (const float*)d_in[11];
  const float* bn6g = (const float*)d_in[12];
  const float* bn6b = (const float*)d_in[13];
  const float* outW = (const float*)d_in[14];
  const float* outb = (const float*)d_in[15];
  float* out = (float*)d_out;

  char* ws = (char*)d_ws;
  int*      ssrc    = (int*)     (ws + OFF_SSRC);
  u32*      rowinfo = (u32*)     (ws + OFF_ROWINFO);
  int*      cursor  = (int*)     (ws + OFF_CURSOR);
  float*    stats   = (float*)   (ws + OFF_STATS);
  float4*   xpad    = (float4*)  (ws + OFF_XPAD);
  _Float16* hA      = (_Float16*)(ws + OFF_HA);
  _Float16* hB      = (_Float16*)(ws + OFF_HB);
  int2*     ebuf    = (int2*)    (ws + OFF_EBUF);   // aliases hA/hB; dead after k_csr

  const int* srcp = ei;
  const int* dstp = ei + EE;

  k_init  <<<1,    256, 0, stream>>>(cursor, stats);
  k_bucket<<<1024, 256, 0, stream>>>(srcp, dstp, cursor, ebuf);
  k_csr   <<<NBUCK,256, 0, stream>>>(ebuf, cursor, ssrc, rowinfo);
  k_xprep <<<1024, 256, 0, stream>>>(x, xpad);

  // conv1 (stats -> slot 0): one float4 request per edge
  k_layer1<<<NBLK, TPB, 0, stream>>>(xpad, rowinfo, ssrc, Wl1, Wr1, b1, hA, stats);

  // conv2..conv7 (16B rows out)
  _Float16* hi = hA; _Float16* ho = hB;
  for(int l=0; l<6; l++){
    const float* st_in = stats + l*SS;
    float* st_out      = stats + (l+1)*SS;
    k_layerk<true,false><<<NBLK, TPB, 0, stream>>>(hi, rowinfo, ssrc,
      Wl + 144*l, Wr + 144*l, bb + 12*l, bng + 12*l, bnb + 12*l, st_in, ho, st_out);
    _Float16* t = hi; hi = ho; ho = t;
  }
  // conv8: store 24B packed rows (streamed by head only; no random gather after this)
  k_layerk<false,true><<<NBLK, TPB, 0, stream>>>(hi, rowinfo, ssrc,
    Wl + 144*6, Wr + 144*6, bb + 12*6, bng + 12*6, bnb + 12*6, stats + 6*SS,
    ho, stats + 7*SS);
  // ho region now holds conv8 output as u64[3] rows; ping-pong 24B buffers
  u64* z_in  = (u64*)ho;
  u64* z_out = (u64*)hi;

  // head: z1 (stats slot 7)
  k_head12<true> <<<NBLK, TPB, 0, stream>>>(z_in, linW, linb, bn6g, bn6b,
                                            stats + 7*SS, z_out, stats + 7*SS);
  { u64* t = z_in; z_in = z_out; z_out = t; }
  // z2 (slot 8)
  k_head12<false><<<NBLK, TPB, 0, stream>>>(z_in, linW, linb, bn6g, bn6b,
                                            stats + 7*SS, z_out, stats + 8*SS);
  { u64* t = z_in; z_in = z_out; z_out = t; }
  // z3 (slot 9)
  k_head12<false><<<NBLK, TPB, 0, stream>>>(z_in, linW, linb, bn6g, bn6b,
                                            stats + 8*SS, z_out, stats + 9*SS);
  { u64* t = z_in; z_in = z_out; z_out = t; }
  // final
  k_out12<<<NBLK, TPB, 0, stream>>>(z_in, bn6g, bn6b, stats + 9*SS, outW, outb, out);
}